// Round 5
// baseline (163.241 us; speedup 1.0000x reference)
//
#include <hip/hip_runtime.h>

typedef _Float16 h16;
typedef __attribute__((ext_vector_type(8))) _Float16 half8;
typedef __attribute__((ext_vector_type(4))) _Float16 half4;
typedef __attribute__((ext_vector_type(4))) float f32x4;
typedef unsigned int u32;
typedef unsigned short u16;
typedef unsigned long long u64;

#define LOG2E 1.44269504088896340736f

__device__ __forceinline__ void gl_lds16(const void* g, void* l){
  __builtin_amdgcn_global_load_lds((const __attribute__((address_space(1))) u32*)g,
                                   (__attribute__((address_space(3))) u32*)l, 16, 0, 0);
}
__device__ __forceinline__ f32x4 mfma16(half8 a, half8 b, f32x4 c){
  return __builtin_amdgcn_mfma_f32_16x16x32_f16(a, b, c, 0, 0, 0);
}
__device__ __forceinline__ f32x4 fzero(){
  f32x4 z = {0.f, 0.f, 0.f, 0.f};
  return z;
}

// ---------------- K0: weights f32 -> f16 ----------------
__global__ void k_cvtw(const float* __restrict__ Wg, const float* __restrict__ Wf,
                       const float* __restrict__ Wh, const float* __restrict__ Wv,
                       h16* __restrict__ o){
  int i = blockIdx.x * 256 + threadIdx.x;     // 0..32767
  o[i]          = (h16)Wg[i];
  o[32768 + i]  = (h16)Wf[i];
  o[65536 + i]  = (h16)Wh[i];
  o[98304 + i]  = (h16)Wv[i];
}

// ---------------- K1: projections  Q,K:[b][p][128]  Vt:[b][128][p] ----------------
// D[d][p] = sum_c W[d][c] * x[c][p]   via  mfma(A=W-frag, B=X'-frag)
__global__ __launch_bounds__(256, 2)
void k_proj(const float* __restrict__ x, const h16* __restrict__ Wgb,
            const h16* __restrict__ Whb, const h16* __restrict__ Wfb,
            h16* __restrict__ Q, h16* __restrict__ K, h16* __restrict__ Vt){
  __shared__ __align__(16) char Xl[64 * 512];   // [64 p][256 c] f16, XOR-swizzled
  int bid = blockIdx.x;
  int b = bid >> 6, p0 = (bid & 63) * 64;
  int tid = threadIdx.x;
  int w = tid >> 6, lane = tid & 63, g4 = lane >> 4, ln = lane & 15;

  // stage x tile transposed -> f16 LDS
  #pragma unroll
  for (int pass = 0; pass < 4; ++pass){
    int idx = pass * 256 + tid;               // 0..1023
    int c4 = idx >> 4, p4 = idx & 15;
    const float* xp = x + ((size_t)b * 256 + c4 * 4) * 4096 + p0 + p4 * 4;
    float4 v0 = *(const float4*)(xp);
    float4 v1 = *(const float4*)(xp + 4096);
    float4 v2 = *(const float4*)(xp + 8192);
    float4 v3 = *(const float4*)(xp + 12288);
    #pragma unroll
    for (int i = 0; i < 4; ++i){
      int row = p4 * 4 + i;
      half4 v = { (h16)((&v0.x)[i]), (h16)((&v1.x)[i]),
                  (h16)((&v2.x)[i]), (h16)((&v3.x)[i]) };
      *(half4*)&Xl[row * 512 + ((c4 * 8) ^ ((row & 7) << 4))] = v;
    }
  }
  __syncthreads();

  // preload all X fragments  B[c][p]: lane reads 8 consecutive c at row p
  half8 xf[4][8];
  #pragma unroll
  for (int pt = 0; pt < 4; ++pt){
    int p = pt * 16 + ln;
    #pragma unroll
    for (int ks = 0; ks < 8; ++ks)
      xf[pt][ks] = *(const half8*)&Xl[p * 512 + (((ks * 4 + g4) ^ (p & 7)) << 4)];
  }

  const h16* Ws0[3] = {Wgb, Whb, Wfb};
  #pragma unroll
  for (int mat = 0; mat < 3; ++mat){
    const h16* Wm = Ws0[mat];
    #pragma unroll
    for (int dtl = 0; dtl < 2; ++dtl){
      int drow = w * 32 + dtl * 16 + ln;
      half8 wf[8];
      #pragma unroll
      for (int ks = 0; ks < 8; ++ks)
        wf[ks] = *(const half8*)&Wm[(size_t)drow * 256 + ks * 32 + g4 * 8];
      #pragma unroll
      for (int pt = 0; pt < 4; ++pt){
        f32x4 acc = fzero();
        #pragma unroll
        for (int ks = 0; ks < 8; ++ks)
          acc = mfma16(wf[ks], xf[pt][ks], acc);
        int p = p0 + pt * 16 + ln;
        int dbase = w * 32 + dtl * 16 + g4 * 4;
        if (mat < 2){
          h16* Dst = (mat == 0) ? Q : K;
          half4 v = { (h16)acc[0], (h16)acc[1], (h16)acc[2], (h16)acc[3] };
          *(half4*)&Dst[((size_t)b * 4096 + p) * 128 + dbase] = v;
        } else {
          #pragma unroll
          for (int r = 0; r < 4; ++r)
            Vt[((size_t)b * 128 + dbase + r) * 4096 + p] = (h16)acc[r];
        }
      }
    }
  }
}

// ---------------- K2: flash attention with KV-split=4 ----------------
// grid 1024: b = bid>>8, qb = (bid>>2)&63, sp = bid&3.  2 waves x 32 q-rows.
__global__ __launch_bounds__(128, 2)
void k_attn(const h16* __restrict__ Q, const h16* __restrict__ K,
            const h16* __restrict__ Vt, h16* __restrict__ Opart,
            float* __restrict__ Mb, float* __restrict__ Lb){
  __shared__ __align__(16) char Kl[16384];      // [64 key][128 d] f16 swz
  __shared__ __align__(16) char Vl[16384];      // [128 d][64 key] f16 swz
  __shared__ __align__(16) char Pl[2][4096];    // per-wave [32 q][64 k] f16 swz

  int bid = blockIdx.x;
  int b = bid >> 8, qb = (bid >> 2) & 63, sp = bid & 3;
  int tid = threadIdx.x;
  int w = tid >> 6, lane = tid & 63, g4 = lane >> 4, ln = lane & 15;
  int q0 = qb * 64 + w * 32;

  // Q fragments (also serve as B-operand of swapped QK^T)
  half8 qf[2][4];
  #pragma unroll
  for (int qt = 0; qt < 2; ++qt)
    #pragma unroll
    for (int ks = 0; ks < 4; ++ks)
      qf[qt][ks] = *(const half8*)&Q[((size_t)b * 4096 + q0 + qt * 16 + ln) * 128 + ks * 32 + g4 * 8];

  f32x4 acc[2][8];
  #pragma unroll
  for (int qt = 0; qt < 2; ++qt)
    #pragma unroll
    for (int dt = 0; dt < 8; ++dt)
      acc[qt][dt] = fzero();
  float mrow[2] = {-1e30f, -1e30f};
  float lrow[2] = {0.f, 0.f};

  for (int t = 0; t < 16; ++t){
    int kv0 = sp * 1024 + t * 64;
    __syncthreads();                            // prev compute done before overwrite
    // stage K tile (pre-swizzled global source, linear LDS dest)
    #pragma unroll
    for (int i = 0; i < 8; ++i){
      int off = i * 2048 + w * 1024 + lane * 16;
      int row = off >> 8, c16 = (off >> 4) & 15;
      gl_lds16(&K[((size_t)b * 4096 + kv0 + row) * 128 + ((c16 ^ (row & 7)) << 3)],
               &Kl[i * 2048 + w * 1024]);
    }
    // stage Vt tile
    #pragma unroll
    for (int i = 0; i < 8; ++i){
      int off = i * 2048 + w * 1024 + lane * 16;
      int row = off >> 7, c16 = (off >> 4) & 7;
      gl_lds16(&Vt[((size_t)b * 128 + row) * 4096 + kv0 + ((c16 ^ (row & 7)) << 3)],
               &Vl[i * 2048 + w * 1024]);
    }
    __syncthreads();                            // vmcnt(0) drained by compiler

    // S^T = mfma(K, Q): tile D[key][q]
    f32x4 s[4][2];
    #pragma unroll
    for (int kt = 0; kt < 4; ++kt)
      #pragma unroll
      for (int qt = 0; qt < 2; ++qt) s[kt][qt] = fzero();
    #pragma unroll
    for (int kt = 0; kt < 4; ++kt){
      int key = kt * 16 + ln;
      #pragma unroll
      for (int ks = 0; ks < 4; ++ks){
        half8 kf = *(const half8*)&Kl[key * 256 + (((ks * 4 + g4) ^ (key & 7)) << 4)];
        #pragma unroll
        for (int qt = 0; qt < 2; ++qt)
          s[kt][qt] = mfma16(kf, qf[qt][ks], s[kt][qt]);
      }
    }

    // online softmax (per lane: q = qt*16+ln, 16 of 64 keys; 2 shfl to reduce)
    #pragma unroll
    for (int qt = 0; qt < 2; ++qt){
      float mx = -1e30f;
      #pragma unroll
      for (int kt = 0; kt < 4; ++kt)
        #pragma unroll
        for (int r = 0; r < 4; ++r) mx = fmaxf(mx, s[kt][qt][r]);
      mx = fmaxf(mx, __shfl_xor(mx, 16));
      mx = fmaxf(mx, __shfl_xor(mx, 32));
      float mnew = fmaxf(mrow[qt], mx);
      float scale = exp2f((mrow[qt] - mnew) * LOG2E);
      mrow[qt] = mnew;
      float ps = 0.f;
      int q = qt * 16 + ln;
      #pragma unroll
      for (int kt = 0; kt < 4; ++kt){
        float e0 = exp2f((s[kt][qt][0] - mnew) * LOG2E);
        float e1 = exp2f((s[kt][qt][1] - mnew) * LOG2E);
        float e2 = exp2f((s[kt][qt][2] - mnew) * LOG2E);
        float e3 = exp2f((s[kt][qt][3] - mnew) * LOG2E);
        ps += (e0 + e1) + (e2 + e3);
        half4 pv = { (h16)e0, (h16)e1, (h16)e2, (h16)e3 };
        // P[q][key]: this lane owns keys kt*16 + g4*4 + (0..3)  -> one b64
        *(half4*)&Pl[w][q * 128 + ((kt * 32 + g4 * 8) ^ ((q & 7) << 4))] = pv;
      }
      ps += __shfl_xor(ps, 16);
      ps += __shfl_xor(ps, 32);
      lrow[qt] = lrow[qt] * scale + ps;
      // rescale accumulator rows (acc row q = qt*16 + g4*4 + r)
      #pragma unroll
      for (int r = 0; r < 4; ++r){
        float sc = __shfl(scale, g4 * 4 + r);
        #pragma unroll
        for (int dt = 0; dt < 8; ++dt) acc[qt][dt][r] *= sc;
      }
    }

    // PV: D[q][d] += P[q][k] * V[k][d]
    #pragma unroll
    for (int st = 0; st < 2; ++st){
      half8 pa[2];
      #pragma unroll
      for (int qt = 0; qt < 2; ++qt){
        int q = qt * 16 + ln;
        pa[qt] = *(const half8*)&Pl[w][q * 128 + (((st * 4 + g4) ^ (q & 7)) << 4)];
      }
      #pragma unroll
      for (int dt = 0; dt < 8; ++dt){
        int row = dt * 16 + ln;
        half8 vf = *(const half8*)&Vl[row * 128 + (((st * 4 + g4) ^ (row & 7)) << 4)];
        #pragma unroll
        for (int qt = 0; qt < 2; ++qt)
          acc[qt][dt] = mfma16(pa[qt], vf, acc[qt][dt]);
      }
    }
  }

  // partial outputs (unnormalized) + m,l
  int pb = (b * 64 + qb) * 4 + sp;
  #pragma unroll
  for (int qt = 0; qt < 2; ++qt)
    #pragma unroll
    for (int dt = 0; dt < 8; ++dt)
      #pragma unroll
      for (int r = 0; r < 4; ++r){
        int qloc = w * 32 + qt * 16 + g4 * 4 + r;
        Opart[(size_t)pb * 8192 + qloc * 128 + dt * 16 + ln] = (h16)acc[qt][dt][r];
      }
  if (lane < 16){
    #pragma unroll
    for (int qt = 0; qt < 2; ++qt){
      int qloc = w * 32 + qt * 16 + lane;
      Mb[pb * 64 + qloc] = mrow[qt];
      Lb[pb * 64 + qloc] = lrow[qt];
    }
  }
}

// ---------------- K3: combine KV-splits ----------------
__global__ __launch_bounds__(256, 4)
void k_comb(const h16* __restrict__ Opart, const float* __restrict__ Mb,
            const float* __restrict__ Lb, h16* __restrict__ O){
  int bid = blockIdx.x;                         // b*64 + qb
  int b = bid >> 6, qb = bid & 63;
  int tid = threadIdx.x;
  int q = tid >> 2, dg = tid & 3;
  int base = bid * 4;
  float m0 = Mb[(base + 0) * 64 + q], m1 = Mb[(base + 1) * 64 + q];
  float m2 = Mb[(base + 2) * 64 + q], m3 = Mb[(base + 3) * 64 + q];
  float mmax = fmaxf(fmaxf(m0, m1), fmaxf(m2, m3));
  float w0 = exp2f((m0 - mmax) * LOG2E), w1 = exp2f((m1 - mmax) * LOG2E);
  float w2 = exp2f((m2 - mmax) * LOG2E), w3 = exp2f((m3 - mmax) * LOG2E);
  float denom = w0 * Lb[(base + 0) * 64 + q] + w1 * Lb[(base + 1) * 64 + q]
              + w2 * Lb[(base + 2) * 64 + q] + w3 * Lb[(base + 3) * 64 + q];
  float inv = 1.f / denom;
  #pragma unroll
  for (int d8 = 0; d8 < 4; ++d8){
    int d = dg * 32 + d8 * 8;
    half8 a0 = *(const half8*)&Opart[((size_t)(base + 0) * 64 + q) * 128 + d];
    half8 a1 = *(const half8*)&Opart[((size_t)(base + 1) * 64 + q) * 128 + d];
    half8 a2 = *(const half8*)&Opart[((size_t)(base + 2) * 64 + q) * 128 + d];
    half8 a3 = *(const half8*)&Opart[((size_t)(base + 3) * 64 + q) * 128 + d];
    half8 o;
    #pragma unroll
    for (int j = 0; j < 8; ++j){
      float v = w0 * (float)a0[j] + w1 * (float)a1[j]
              + w2 * (float)a2[j] + w3 * (float)a3[j];
      o[j] = (h16)(v * inv);
    }
    *(half8*)&O[((size_t)b * 4096 + qb * 64 + q) * 128 + d] = o;
  }
}

// ---------------- K4: out = x + lambda * Wv @ O ----------------
__global__ __launch_bounds__(256, 2)
void k_oproj(const float* __restrict__ x, const h16* __restrict__ Wvb,
             const h16* __restrict__ O, const float* __restrict__ lamp,
             float* __restrict__ y){
  __shared__ __align__(16) char Ol[16384];      // [64 p][128 d] f16 swz
  int bid = blockIdx.x;
  int b = bid >> 6, p0 = (bid & 63) * 64;
  int tid = threadIdx.x;
  int w = tid >> 6, lane = tid & 63, g4 = lane >> 4, ln = lane & 15;
  float lam = lamp[0];

  #pragma unroll
  for (int i = 0; i < 4; ++i){
    int off = i * 4096 + w * 1024 + lane * 16;
    int row = off >> 8, c16 = (off >> 4) & 15;
    gl_lds16(&O[((size_t)b * 4096 + p0 + row) * 128 + ((c16 ^ (row & 7)) << 3)],
             &Ol[i * 4096 + w * 1024]);
  }
  __syncthreads();

  half8 of[4][4];
  #pragma unroll
  for (int pt = 0; pt < 4; ++pt){
    int p = pt * 16 + ln;
    #pragma unroll
    for (int ks = 0; ks < 4; ++ks)
      of[pt][ks] = *(const half8*)&Ol[p * 256 + (((ks * 4 + g4) ^ (p & 7)) << 4)];
  }
  #pragma unroll
  for (int ctl = 0; ctl < 4; ++ctl){
    int crow = w * 64 + ctl * 16 + ln;
    half8 wf[4];
    #pragma unroll
    for (int ks = 0; ks < 4; ++ks)
      wf[ks] = *(const half8*)&Wvb[(size_t)crow * 128 + ks * 32 + g4 * 8];
    #pragma unroll
    for (int pt = 0; pt < 4; ++pt){
      f32x4 a = fzero();
      #pragma unroll
      for (int ks = 0; ks < 4; ++ks) a = mfma16(wf[ks], of[pt][ks], a);
      int p = p0 + pt * 16 + ln;
      int c = w * 64 + ctl * 16 + g4 * 4;
      #pragma unroll
      for (int r = 0; r < 4; ++r){
        size_t idx = ((size_t)b * 256 + c + r) * 4096 + p;
        y[idx] = x[idx] + lam * a[r];
      }
    }
  }
}

extern "C" void kernel_launch(void* const* d_in, const int* in_sizes, int n_in,
                              void* d_out, int out_size, void* d_ws, size_t ws_size,
                              hipStream_t stream) {
  const float* x   = (const float*)d_in[0];
  const float* Wg  = (const float*)d_in[1];
  const float* Wf  = (const float*)d_in[2];
  const float* Wh  = (const float*)d_in[3];
  const float* Wv  = (const float*)d_in[4];
  const float* lam = (const float*)d_in[5];

  h16* Wall  = (h16*)d_ws;                 // 131072 h16 (Wg,Wf,Wh,Wv f16)
  h16* Qb    = Wall + 131072;              // [4][4096][128]
  h16* Kb    = Qb + 2097152;               // [4][4096][128]
  h16* Vtb   = Kb + 2097152;               // [4][128][4096]
  h16* Ob    = Vtb + 2097152;              // [4][4096][128]
  h16* Opart = Ob + 2097152;               // [1024][64][128]
  float* Mb  = (float*)(Opart + 8388608);  // [1024][64]
  float* Lb  = Mb + 65536;                 // [1024][64]

  k_cvtw<<<128, 256, 0, stream>>>(Wg, Wf, Wh, Wv, Wall);
  k_proj<<<256, 256, 0, stream>>>(x, Wall /*Wg*/, Wall + 65536 /*Wh*/, Wall + 32768 /*Wf*/,
                                  Qb, Kb, Vtb);
  k_attn<<<1024, 128, 0, stream>>>(Qb, Kb, Vtb, Opart, Mb, Lb);
  k_comb<<<256, 256, 0, stream>>>(Opart, Mb, Lb, Ob);
  k_oproj<<<256, 256, 0, stream>>>(x, Wall + 98304 /*Wv*/, Ob, lam, (float*)d_out);
}